// Round 9
// baseline (74.536 us; speedup 1.0000x reference)
//
#include <hip/hip_runtime.h>
#include <hip/hip_bf16.h>
#include <stdint.h>

// Problem constants (B=8, C=512, H=W=32, N=4)
constexpr int BN = 32;     // B*N batch-heads
constexpr int Cn = 128;    // channels per head
constexpr int L  = 1024;   // H*W
constexpr int CC = 512;    // C
constexpr int BB = 8;      // B

typedef __bf16 bf16x8 __attribute__((ext_vector_type(8)));
typedef float  f32x4  __attribute__((ext_vector_type(4)));
typedef unsigned short u16x8 __attribute__((ext_vector_type(8)));

__device__ inline unsigned short f2bf(float f) {
    unsigned int x = __float_as_uint(f);
    x += 0x7fffu + ((x >> 16) & 1u);   // round-to-nearest-even
    return (unsigned short)(x >> 16);
}

// async global->LDS, 16B per lane (dest = wave-uniform base + lane*16)
__device__ inline void gl_lds16(const void* g, void* l) {
    typedef __attribute__((address_space(1))) const unsigned int GU;
    typedef __attribute__((address_space(3))) unsigned int LU;
    __builtin_amdgcn_global_load_lds((GU*)g, (LU*)l, 16, 0, 0);
}

// ---------------------------------------------------------------------------
// Kernel 0 (v2): xsplit + wsplit fused.
// Blocks 0..1023: transpose+split x -> xT[l][c] hi/lo bf16, rows chunk-
//   swizzled for MFMA B-frags: 16B chunk j of row l stored at j^(l&15).
//   Block = (slab 64, l-chunk of 64). Thread: l = t&63, q = t>>6; 4 c-octs.
//   Reads coalesced (lanes = consecutive l, 256B bursts); each row's 16
//   chunks written by 4 same-block threads -> L2 write-merge.
// Blocks 1024..1087: split w1..w4 into whi/wlo (plain [mat][o][c]).
// ---------------------------------------------------------------------------
__global__ __launch_bounds__(256)
void xsplit_kernel(const float* __restrict__ first, const float* __restrict__ second,
                   const float* __restrict__ w1, const float* __restrict__ w2,
                   const float* __restrict__ w3, const float* __restrict__ w4,
                   unsigned short* __restrict__ xhi, unsigned short* __restrict__ xlo,
                   unsigned short* __restrict__ whi, unsigned short* __restrict__ wlo)
{
    const int blk = blockIdx.x;
    const int t   = threadIdx.x;

    if (blk >= 1024) {   // ---- wsplit part ----
        int idx = ((blk - 1024) * 256 + t) * 4;   // 0..65532
        int mat = idx >> 14;
        int off = idx & 16383;
        const float* w = (mat == 0) ? w1 : (mat == 1) ? w2 : (mat == 2) ? w3 : w4;
        float4 v = *(const float4*)&w[off];
        ushort4 hi, lo;
        hi.x = f2bf(v.x); lo.x = f2bf(v.x - __uint_as_float((unsigned)hi.x << 16));
        hi.y = f2bf(v.y); lo.y = f2bf(v.y - __uint_as_float((unsigned)hi.y << 16));
        hi.z = f2bf(v.z); lo.z = f2bf(v.z - __uint_as_float((unsigned)hi.z << 16));
        hi.w = f2bf(v.w); lo.w = f2bf(v.w - __uint_as_float((unsigned)hi.w << 16));
        *(ushort4*)&whi[idx] = hi;
        *(ushort4*)&wlo[idx] = lo;
        return;
    }

    // ---- x transpose+split part ----
    const int slab   = blk >> 4;          // src*32 + bn (0..63)
    const int lchunk = blk & 15;          // 64-row l chunk
    const int src    = slab >> 5;
    const int bn     = slab & 31;
    const float* xs = (src ? second : first) + (size_t)bn * Cn * L;

    const int l     = t & 63;
    const int q     = t >> 6;             // 0..3 (4 c-octs each)
    const int lg    = lchunk * 64 + l;    // global l
    const size_t rowbase = (size_t)slab * (L * Cn) + (size_t)lg * Cn;

    #pragma unroll
    for (int i = 0; i < 4; ++i) {
        const int coct = q * 4 + i;       // 0..15
        float v[8];
        #pragma unroll
        for (int j = 0; j < 8; ++j)
            v[j] = xs[(size_t)(coct * 8 + j) * L + lg];
        u16x8 hi, lo;
        #pragma unroll
        for (int j = 0; j < 8; ++j) {
            unsigned short h = f2bf(v[j]);
            hi[j] = h;
            lo[j] = f2bf(v[j] - __uint_as_float((unsigned)h << 16));
        }
        const int pos = (coct ^ (lg & 15)) * 8;
        *(u16x8*)&xhi[rowbase + pos] = hi;
        *(u16x8*)&xlo[rowbase + pos] = lo;
    }
}

// ---------------------------------------------------------------------------
// Kernel 1 (v7): attn-clone MFMA projections.
//   P[l][o] = sum_c w[o][c]*x[c][l] via 3-pass split bf16 MFMA
//   (w_hi*x_hi + w_lo*x_hi + w_hi*x_lo), f32 acc, bf16 store in the attn
//   chunk-swizzle format (chunk j of row l at j^(l&7)).
// grid = 512 = (bn32, src2, lt8: 128 l); 512 thr = 8 waves;
// wave = (mat2, oh2, ogh2) -> 32 o columns each. w-frags (hi+lo, og2 x kk4 =
// 16 bf16x8 = 64 VGPR) resident. 4 strips of 32 l, double-buffered via
// gl_lds16 LINEAR copies from pre-swizzled xT (attn's proven staging path).
// LDS: xh/xl[2 buf][32 rows * 128c] bf16 = 32 KB.
// ---------------------------------------------------------------------------
__global__ __launch_bounds__(512, 4)
void proj_kernel(const unsigned short* __restrict__ xhi,
                 const unsigned short* __restrict__ xlo,
                 const unsigned short* __restrict__ whi,
                 const unsigned short* __restrict__ wlo,
                 unsigned short* __restrict__ outP)
{
    __shared__ unsigned short xh[2][32 * 128];   // 8 KB each buf
    __shared__ unsigned short xl[2][32 * 128];

    const int p   = blockIdx.x;
    const int lt  = p & 7;             // 128-row l tile
    const int src = (p >> 3) & 1;
    const int bn  = p >> 4;

    const int slab = src * 32 + bn;
    const unsigned short* XH = xhi + (size_t)slab * (L * Cn);
    const unsigned short* XL = xlo + (size_t)slab * (L * Cn);

    const int tid  = threadIdx.x;
    const int lane = tid & 63;
    const int wid  = tid >> 6;         // 0..7
    const int mat  = wid & 1;
    const int oh   = (wid >> 1) & 1;
    const int ogh  = wid >> 2;         // 0..1
    const int r16  = lane & 15;
    const int g    = lane >> 4;

    const int mi = mat * 2 + src;      // matrix index 0..3
    const unsigned short* WHm = whi + mi * 16384;
    const unsigned short* WLm = wlo + mi * 16384;
    unsigned short* Pout = outP + (size_t)(mi * BN + bn) * (L * Cn);

    const int obase = oh * 64 + ogh * 32;

    // ---- resident w-frags: [og2][kk4] hi+lo = 64 VGPR ----
    bf16x8 ah[2][4], al[2][4];
    #pragma unroll
    for (int og = 0; og < 2; ++og)
        #pragma unroll
        for (int kk = 0; kk < 4; ++kk) {
            int o = obase + og * 16 + r16;
            int c = kk * 32 + g * 8;
            ah[og][kk] = *(const bf16x8*)&WHm[o * 128 + c];
            al[og][kk] = *(const bf16x8*)&WLm[o * 128 + c];
        }

    // ---- staging: linear 8 KB copy per part per strip (swizzle pre-baked) ----
    auto STAGE = [&](int buf, int s) {
        const size_t src_off = ((size_t)(lt * 128 + s * 32)) * Cn + tid * 8;
        gl_lds16(XH + src_off, &xh[buf][tid * 8]);
        gl_lds16(XL + src_off, &xl[buf][tid * 8]);
    };

    STAGE(0, 0);
    __syncthreads();

    #pragma unroll
    for (int s = 0; s < 4; ++s) {
        const int buf = s & 1;
        if (s < 3) STAGE(buf ^ 1, s + 1);   // async loads in flight during compute

        f32x4 acc[2][2];                    // [og][lg] = 16 VGPR
        #pragma unroll
        for (int a = 0; a < 2; ++a)
            #pragma unroll
            for (int b = 0; b < 2; ++b) acc[a][b] = (f32x4){0.f, 0.f, 0.f, 0.f};

        #pragma unroll
        for (int kk = 0; kk < 4; ++kk) {
            bf16x8 bh[2], bl[2];
            #pragma unroll
            for (int lg = 0; lg < 2; ++lg) {
                int row  = lg * 16 + r16;
                int slot = ((kk << 2) + g) ^ r16;
                bh[lg] = *(const bf16x8*)&xh[buf][row * 128 + slot * 8];
                bl[lg] = *(const bf16x8*)&xl[buf][row * 128 + slot * 8];
            }
            #pragma unroll
            for (int og = 0; og < 2; ++og)
                #pragma unroll
                for (int lg = 0; lg < 2; ++lg) {
                    f32x4 a = acc[og][lg];
                    a = __builtin_amdgcn_mfma_f32_16x16x32_bf16(ah[og][kk], bh[lg], a, 0, 0, 0);
                    a = __builtin_amdgcn_mfma_f32_16x16x32_bf16(al[og][kk], bh[lg], a, 0, 0, 0);
                    a = __builtin_amdgcn_mfma_f32_16x16x32_bf16(ah[og][kk], bl[lg], a, 0, 0, 0);
                    acc[og][lg] = a;
                }
        }

        // ---- store P strip (bf16, attn swizzle: chunk j of row l at j^(l&7)) ----
        #pragma unroll
        for (int og = 0; og < 2; ++og)
            #pragma unroll
            for (int lg = 0; lg < 2; ++lg) {
                int o0 = obase + og * 16 + g * 4;        // reg r -> o0+r
                int l  = lt * 128 + s * 32 + lg * 16 + r16;
                f32x4 a = acc[og][lg];
                ushort4 st;
                st.x = f2bf(a.x); st.y = f2bf(a.y);
                st.z = f2bf(a.z); st.w = f2bf(a.w);
                int pos = (((o0 >> 3) ^ (l & 7)) << 3) | (o0 & 7);
                *(ushort4*)&Pout[(size_t)l * 128 + pos] = st;
            }

        __syncthreads();                    // next-strip staging complete
    }
}

// ---------------------------------------------------------------------------
// Kernel 2: MFMA attention with no-max softmax (shift 8), m-split in halves.
//   (unchanged)
// ---------------------------------------------------------------------------
__global__ __launch_bounds__(256, 2)
void attn_kernel(const unsigned short* __restrict__ Pb,
                 float* __restrict__ Dp, float* __restrict__ Rp)
{
    __shared__ char smem[2][2][16384];   // [buf][q/v2][64 rows * 256B]

    const int p   = blockIdx.x;          // 0..511
    const int xcd = p & 7;
    const int jj  = p >> 3;              // 0..63
    const int bn  = xcd * 4 + (jj & 3);  // all blocks of a bn on one XCD
    const int lt  = (jj >> 2) & 7;       // 0..7 (128-row l tile)
    const int mh  = jj >> 5;             // 0..1 (m half)

    const int tid  = threadIdx.x;
    const int lane = tid & 63;
    const int w    = tid >> 6;           // wave 0..3
    const int r16  = lane & 15;
    const int g    = lane >> 4;          // 0..3
    const int swz  = lane & 7;

    const size_t slab = (size_t)L * Cn;
    const unsigned short* Kt  = Pb + (size_t)(0 * BN + bn) * slab;
    const unsigned short* Qt  = Pb + (size_t)(1 * BN + bn) * slab;
    const unsigned short* V1t = Pb + (size_t)(2 * BN + bn) * slab;
    const unsigned short* V2t = Pb + (size_t)(3 * BN + bn) * slab;

    const int lbase = lt * 128;

    // A-frags for K and V1, kept in registers the whole kernel.
    bf16x8 ka[2][4], va[2][4];
    #pragma unroll
    for (int i = 0; i < 2; ++i)
        #pragma unroll
        for (int kk = 0; kk < 4; ++kk) {
            int row = lbase + w * 32 + i * 16 + r16;
            int cp = ((kk << 2) + g) ^ swz;           // swizzled chunk (row&7 == swz)
            ka[i][kk] = *(const bf16x8*)(Kt  + (size_t)row * 128 + cp * 8);
            va[i][kk] = *(const bf16x8*)(V1t + (size_t)row * 128 + cp * 8);
        }

    const f32x4 z = {0.f, 0.f, 0.f, 0.f};
    f32x4 Dv[2] = {z, z};
    f32x4 Rv[2] = {z, z};

    auto STAGE = [&](int buf, int t) {
        const int m0 = mh * 512 + t * 64;
        const char* qs = (const char*)Qt  + (size_t)m0 * 256;
        const char* vs = (const char*)V2t + (size_t)m0 * 256;
        char* qd = &smem[buf][0][0];
        char* vd = &smem[buf][1][0];
        #pragma unroll
        for (int it = 0; it < 4; ++it) {
            gl_lds16(qs + tid * 16 + it * 4096, qd + tid * 16 + it * 4096);
            gl_lds16(vs + tid * 16 + it * 4096, vd + tid * 16 + it * 4096);
        }
    };

    auto COMPUTE = [&](int buf) {
        const char* qb = &smem[buf][0][0];
        const char* vb = &smem[buf][1][0];
        #pragma unroll
        for (int cg = 0; cg < 4; ++cg) {
            const int brow = cg * 16 + r16;           // brow&7 == swz
            const int rbase = brow * 256;
            bf16x8 qf[4], vf[4];
            #pragma unroll
            for (int kk = 0; kk < 4; ++kk) {
                int off = rbase + ((((kk << 2) + g) ^ swz) << 4);
                qf[kk] = *(const bf16x8*)(qb + off);
                vf[kk] = *(const bf16x8*)(vb + off);
            }
            f32x4 s0 = z, s1 = z, u0 = z, u1 = z;
            #pragma unroll
            for (int kk = 0; kk < 4; ++kk) {
                s0 = __builtin_amdgcn_mfma_f32_16x16x32_bf16(ka[0][kk], qf[kk], s0, 0, 0, 0);
                s1 = __builtin_amdgcn_mfma_f32_16x16x32_bf16(ka[1][kk], qf[kk], s1, 0, 0, 0);
                u0 = __builtin_amdgcn_mfma_f32_16x16x32_bf16(va[0][kk], vf[kk], u0, 0, 0, 0);
                u1 = __builtin_amdgcn_mfma_f32_16x16x32_bf16(va[1][kk], vf[kk], u1, 0, 0, 0);
            }
            f32x4 e0, e1;
            e0.x = __expf(s0.x - 8.f); e0.y = __expf(s0.y - 8.f);
            e0.z = __expf(s0.z - 8.f); e0.w = __expf(s0.w - 8.f);
            e1.x = __expf(s1.x - 8.f); e1.y = __expf(s1.y - 8.f);
            e1.z = __expf(s1.z - 8.f); e1.w = __expf(s1.w - 8.f);
            Dv[0] += e0;      Dv[1] += e1;
            Rv[0] += e0 * u0; Rv[1] += e1 * u1;
        }
    };

    STAGE(0, 0);
    __syncthreads();                       // drains vmcnt before first compute
    for (int t = 0; t < 8; ++t) {
        if (t < 7) STAGE((t + 1) & 1, t + 1);   // loads in flight during compute
        COMPUTE(t & 1);
        __syncthreads();                   // drains vmcnt(0): next tile ready
    }

    // butterfly-sum D,R over the 16 lanes sharing each row group
    #pragma unroll
    for (int off = 8; off >= 1; off >>= 1) {
        #pragma unroll
        for (int i = 0; i < 2; ++i) {
            #pragma unroll
            for (int r = 0; r < 4; ++r) {
                Dv[i][r] += __shfl_xor(Dv[i][r], off);
                Rv[i][r] += __shfl_xor(Rv[i][r], off);
            }
        }
    }
    if (r16 == 0) {
        #pragma unroll
        for (int i = 0; i < 2; ++i)
            #pragma unroll
            for (int r = 0; r < 4; ++r) {
                int l = lbase + w * 32 + i * 16 + g * 4 + r;
                size_t idx = (size_t)mh * BN * L + (size_t)bn * L + l;
                Dp[idx] = Dv[i][r];
                Rp[idx] = Rv[i][r];
            }
    }
}

// ---------------------------------------------------------------------------
// Kernel 3: res = (R0+R1)/(D0+D1).  32768 elems -> 128 blocks x 256 thr.
// ---------------------------------------------------------------------------
__global__ __launch_bounds__(256)
void combine_kernel(const float* __restrict__ Dp, const float* __restrict__ Rp,
                    float* __restrict__ res)
{
    int i = blockIdx.x * 256 + threadIdx.x;
    float d = Dp[i] + Dp[BN * L + i];
    float r = Rp[i] + Rp[BN * L + i];
    res[i] = r / d;
}

// ---------------------------------------------------------------------------
// Kernel 4: out[b][o][hw] = relu( sum_n w5[o][n] * res[b*4+n][hw] )
// ---------------------------------------------------------------------------
__global__ __launch_bounds__(256)
void out_kernel(const float* __restrict__ res, const float* __restrict__ w5,
                float* __restrict__ out)
{
    const int blk = blockIdx.x;
    const int o = blk & 511;
    const int b = blk >> 9;
    const float4 wv = *(const float4*)&w5[o * 4];

    const float* r0 = res + (size_t)(b * 4 + 0) * L;
    const float* r1 = res + (size_t)(b * 4 + 1) * L;
    const float* r2 = res + (size_t)(b * 4 + 2) * L;
    const float* r3 = res + (size_t)(b * 4 + 3) * L;

    const int hw = threadIdx.x * 4;
    float4 a0 = *(const float4*)&r0[hw];
    float4 a1 = *(const float4*)&r1[hw];
    float4 a2 = *(const float4*)&r2[hw];
    float4 a3 = *(const float4*)&r3[hw];

    float4 ov;
    ov.x = fmaxf(0.f, wv.x * a0.x + wv.y * a1.x + wv.z * a2.x + wv.w * a3.x);
    ov.y = fmaxf(0.f, wv.x * a0.y + wv.y * a1.y + wv.z * a2.y + wv.w * a3.y);
    ov.z = fmaxf(0.f, wv.x * a0.z + wv.y * a1.z + wv.z * a2.z + wv.w * a3.z);
    ov.w = fmaxf(0.f, wv.x * a0.w + wv.y * a1.w + wv.z * a2.w + wv.w * a3.w);

    *(float4*)&out[(size_t)blk * 1024 + hw] = ov;
}

// ---------------------------------------------------------------------------
extern "C" void kernel_launch(void* const* d_in, const int* in_sizes, int n_in,
                              void* d_out, int out_size, void* d_ws, size_t ws_size,
                              hipStream_t stream)
{
    const float* first  = (const float*)d_in[0];
    const float* second = (const float*)d_in[1];
    const float* w1 = (const float*)d_in[2];
    const float* w2 = (const float*)d_in[3];
    const float* w3 = (const float*)d_in[4];
    const float* w4 = (const float*)d_in[5];
    const float* w5 = (const float*)d_in[6];
    float* out = (float*)d_out;

    const size_t slabElems = (size_t)L * Cn;                 // 131072
    const size_t projBytes = (size_t)4 * BN * slabElems * 2; // 32 MB
    unsigned short* P   = (unsigned short*)d_ws;
    float* Dp  = (float*)((char*)d_ws + projBytes);
    float* Rp  = Dp + 2 * BN * L;
    float* res = Rp + 2 * BN * L;
    unsigned short* whi = (unsigned short*)(res + BN * L);
    unsigned short* wlo = whi + 4 * 16384;
    unsigned short* xhi = wlo + 4 * 16384;
    unsigned short* xlo = xhi + 64 * slabElems;              // 16.8 MB each

    xsplit_kernel<<<dim3(1088), dim3(256), 0, stream>>>(
        first, second, w1, w2, w3, w4, xhi, xlo, whi, wlo);
    proj_kernel<<<dim3(512), dim3(512), 0, stream>>>(xhi, xlo, whi, wlo, P);
    attn_kernel<<<dim3(512), dim3(256), 0, stream>>>(P, Dp, Rp);
    combine_kernel<<<dim3(BN * L / 256), dim3(256), 0, stream>>>(Dp, Rp, res);
    out_kernel<<<dim3(BB * CC), dim3(256), 0, stream>>>(res, w5, out);
}